// Round 1
// baseline (612.882 us; speedup 1.0000x reference)
//
#include <hip/hip_runtime.h>

#define N 2048
#define NG 8

__device__ __forceinline__ float lrelu(float x) { return x > 0.f ? x : 0.2f * x; }

// ---------- prep: zero colSum/colCnt, compute we1[4], we2 ----------
__global__ __launch_bounds__(256) void weZeroK(float* __restrict__ zbase,
                                               const float* __restrict__ We1, const float* __restrict__ att_e1,
                                               const float* __restrict__ We2, const float* __restrict__ att_e2,
                                               float* __restrict__ we) {
  int tid = threadIdx.x;
  int i = blockIdx.x * 256 + tid;
  if (i < 2 * N) zbase[i] = 0.f;
  if (blockIdx.x == 0) {
    float v1 = We1[tid] * att_e1[tid];
#pragma unroll
    for (int off = 32; off > 0; off >>= 1) v1 += __shfl_down(v1, off);
    int lane = tid & 63, wid = tid >> 6;
    if (lane == 0) we[wid] = v1;
    float v2 = (tid < 64) ? We2[tid] * att_e2[tid] : 0.f;
#pragma unroll
    for (int off = 32; off > 0; off >>= 1) v2 += __shfl_down(v2, off);
    if (tid == 0) we[4] = v2;
  }
}

// ---------- agg: 1x1 conv, edge_attr, transposed relu(agg), column stats ----------
__global__ __launch_bounds__(256) void aggK(const float* __restrict__ attn,
                                            const float* __restrict__ w_agg,
                                            const float* __restrict__ b_agg,
                                            float* __restrict__ edge_out,
                                            float* __restrict__ aggT,
                                            float* __restrict__ colSum,
                                            float* __restrict__ colCnt) {
  __shared__ float tile[32][33];
  __shared__ float wsh[12];
  __shared__ float cs[32];
  __shared__ float cc[32];
  int tx = threadIdx.x, ty = threadIdx.y;
  int tid = ty * 32 + tx;
  if (tid < 12) wsh[tid] = w_agg[tid];
  if (tid < 32) { cs[tid] = 0.f; cc[tid] = 0.f; }
  __syncthreads();
  int i0 = blockIdx.y * 32, j0 = blockIdx.x * 32;
  int j = j0 + tx;
  float bb = b_agg[0];
#pragma unroll
  for (int r = 0; r < 4; ++r) {
    int li = ty + 8 * r;
    int i = i0 + li;
    const float* p = attn + (size_t)i * N + j;
    float v = bb;
#pragma unroll
    for (int k = 0; k < 12; ++k) v += wsh[k] * p[(size_t)k * N * N];
    float e = v > 0.f ? v : 0.f;
    edge_out[(size_t)i * N + j] = e;
    tile[li][tx] = e;
    if (e > 0.f && i != j) { atomicAdd(&cs[tx], e); atomicAdd(&cc[tx], 1.f); }
  }
  __syncthreads();
#pragma unroll
  for (int r = 0; r < 4; ++r) {
    int lj = ty + 8 * r;
    aggT[(size_t)(j0 + lj) * N + i0 + tx] = tile[tx][lj];
  }
  if (tid < 32) {
    atomicAdd(&colSum[j0 + tid], cs[tid]);
    atomicAdd(&colCnt[j0 + tid], cc[tid]);
  }
}

// ---------- meanE per dst ----------
__global__ __launch_bounds__(256) void meanK(const float* __restrict__ colSum,
                                             const float* __restrict__ colCnt,
                                             float* __restrict__ meanE) {
  int d = blockIdx.x * 256 + threadIdx.x;
  if (d < N) { float c = colCnt[d]; meanE[d] = c > 0.f ? colSum[d] / c : 0.f; }
}

// ---------- layer1 features: h1 = x @ W1, a_s1, a_d1 ----------
__global__ __launch_bounds__(256) void h1K(const float* __restrict__ x, const float* __restrict__ W1,
                                           const float* __restrict__ att_src1, const float* __restrict__ att_dst1,
                                           float* __restrict__ h1, float* __restrict__ a_s1, float* __restrict__ a_d1) {
  __shared__ float xr[4][128];
  int tid = threadIdx.x;
  int n0 = blockIdx.x * 4;
  for (int t = tid; t < 512; t += 256) xr[t >> 7][t & 127] = x[n0 * 128 + t];
  __syncthreads();
  float acc[4] = {0.f, 0.f, 0.f, 0.f};
  for (int k = 0; k < 128; ++k) {
    float wv = W1[k * 256 + tid];
#pragma unroll
    for (int r = 0; r < 4; ++r) acc[r] += xr[r][k] * wv;
  }
  float asw = att_src1[tid], adw = att_dst1[tid];
  int lane = tid & 63, head = tid >> 6;
#pragma unroll
  for (int r = 0; r < 4; ++r) {
    h1[(size_t)(n0 + r) * 256 + tid] = acc[r];
    float ps = acc[r] * asw, pd = acc[r] * adw;
#pragma unroll
    for (int off = 32; off > 0; off >>= 1) { ps += __shfl_down(ps, off); pd += __shfl_down(pd, off); }
    if (lane == 0) { a_s1[(n0 + r) * 4 + head] = ps; a_d1[(n0 + r) * 4 + head] = pd; }
  }
}

// ---------- layer1 softmax stats: per-dst per-head max + sumexp ----------
__global__ __launch_bounds__(256) void stats1K(const float* __restrict__ aggT, const float* __restrict__ a_s1,
                                               const float* __restrict__ a_d1, const float* __restrict__ meanE,
                                               const float* __restrict__ we,
                                               float* __restrict__ m1, float* __restrict__ z1) {
  int tid = threadIdx.x;
  int d = blockIdx.x;
  float4 ad = *(const float4*)(a_d1 + d * 4);
  float me = meanE[d];
  float w0 = we[0], w1 = we[1], w2 = we[2], w3 = we[3];
  float m[4] = {-1e30f, -1e30f, -1e30f, -1e30f};
  float z[4] = {0.f, 0.f, 0.f, 0.f};
  const float* arow = aggT + (size_t)d * N;
#pragma unroll 1
  for (int s = tid; s < N; s += 256) {
    float av = arow[s];
    float ev; bool inc;
    if (s == d) { ev = me; inc = true; } else { ev = av; inc = av > 0.f; }
    if (inc) {
      float4 as4 = *(const float4*)(a_s1 + s * 4);
      float l0 = lrelu(as4.x + ad.x + ev * w0);
      float l1 = lrelu(as4.y + ad.y + ev * w1);
      float l2 = lrelu(as4.z + ad.z + ev * w2);
      float l3 = lrelu(as4.w + ad.w + ev * w3);
      float nm;
      nm = fmaxf(m[0], l0); z[0] = z[0] * __expf(m[0] - nm) + __expf(l0 - nm); m[0] = nm;
      nm = fmaxf(m[1], l1); z[1] = z[1] * __expf(m[1] - nm) + __expf(l1 - nm); m[1] = nm;
      nm = fmaxf(m[2], l2); z[2] = z[2] * __expf(m[2] - nm) + __expf(l2 - nm); m[2] = nm;
      nm = fmaxf(m[3], l3); z[3] = z[3] * __expf(m[3] - nm) + __expf(l3 - nm); m[3] = nm;
    }
  }
#pragma unroll
  for (int off = 32; off > 0; off >>= 1) {
#pragma unroll
    for (int h = 0; h < 4; ++h) {
      float mo = __shfl_down(m[h], off);
      float zo = __shfl_down(z[h], off);
      float nm = fmaxf(m[h], mo);
      z[h] = z[h] * __expf(m[h] - nm) + zo * __expf(mo - nm);
      m[h] = nm;
    }
  }
  __shared__ float sm[4][4], sz[4][4];
  int lane = tid & 63, wid = tid >> 6;
  if (lane == 0) {
#pragma unroll
    for (int h = 0; h < 4; ++h) { sm[wid][h] = m[h]; sz[wid][h] = z[h]; }
  }
  __syncthreads();
  if (tid < 4) {
    float M = -1e30f, Z = 0.f;
#pragma unroll
    for (int w = 0; w < 4; ++w) {
      float mo = sm[w][tid], zo = sz[w][tid];
      float nm = fmaxf(M, mo);
      Z = Z * __expf(M - nm) + zo * __expf(mo - nm);
      M = nm;
    }
    m1[d * 4 + tid] = M; z1[d * 4 + tid] = Z;
  }
}

// ---------- layer1 PV: partials[q][d][c] = sum_{s in chunk q} p(s,d,h(c)) * h1[s][c] ----------
__global__ __launch_bounds__(256) void pv1K(const float* __restrict__ aggT, const float* __restrict__ h1,
                                            const float* __restrict__ a_s1, const float* __restrict__ a_d1,
                                            const float* __restrict__ m1, const float* __restrict__ meanE,
                                            const float* __restrict__ we, float* __restrict__ partials) {
  __shared__ float pL[4][64][17];   // [head][dd][ss]
  __shared__ float hT[256][17];     // [c][ss]
  int tid = threadIdx.x;
  int d0 = blockIdx.x * 64;
  int sBeg = blockIdx.y * 256;
  int dg = tid & 7;       // FMA: dd = dg*8 + di
  int cg = tid >> 3;      // FMA: c = cg*8 + ci ; head = cg>>3 (wave-uniform)
  int hh = cg >> 3;
  int ssp = tid & 15, dq = tid >> 4;  // p-compute: dd = dq*4 + q
  float w4x = we[0], w4y = we[1], w4z = we[2], w4w = we[3];
  float acc[8][8];
#pragma unroll
  for (int i = 0; i < 8; ++i)
#pragma unroll
    for (int j = 0; j < 8; ++j) acc[i][j] = 0.f;

#pragma unroll 1
  for (int s0 = sBeg; s0 < sBeg + 256; s0 += 16) {
#pragma unroll
    for (int r = 0; r < 16; ++r) hT[tid][r] = h1[(size_t)(s0 + r) * 256 + tid];
    {
      int s = s0 + ssp;
      float4 as4 = *(const float4*)(a_s1 + s * 4);
#pragma unroll
      for (int q = 0; q < 4; ++q) {
        int dd = dq * 4 + q;
        int d = d0 + dd;
        float av = aggT[(size_t)d * N + s];
        float ev; bool inc;
        if (s == d) { ev = meanE[d]; inc = true; } else { ev = av; inc = av > 0.f; }
        float4 ad4 = *(const float4*)(a_d1 + d * 4);
        float4 m4 = *(const float4*)(m1 + d * 4);
        pL[0][dd][ssp] = inc ? __expf(lrelu(as4.x + ad4.x + ev * w4x) - m4.x) : 0.f;
        pL[1][dd][ssp] = inc ? __expf(lrelu(as4.y + ad4.y + ev * w4y) - m4.y) : 0.f;
        pL[2][dd][ssp] = inc ? __expf(lrelu(as4.z + ad4.z + ev * w4z) - m4.z) : 0.f;
        pL[3][dd][ssp] = inc ? __expf(lrelu(as4.w + ad4.w + ev * w4w) - m4.w) : 0.f;
      }
    }
    __syncthreads();
#pragma unroll
    for (int ss = 0; ss < 16; ++ss) {
      float hv[8], pv[8];
#pragma unroll
      for (int i = 0; i < 8; ++i) hv[i] = hT[cg * 8 + i][ss];
#pragma unroll
      for (int i = 0; i < 8; ++i) pv[i] = pL[hh][dg * 8 + i][ss];
#pragma unroll
      for (int di = 0; di < 8; ++di)
#pragma unroll
        for (int ci = 0; ci < 8; ++ci) acc[di][ci] += pv[di] * hv[ci];
    }
    __syncthreads();
  }
  float* outp = partials + (size_t)blockIdx.y * ((size_t)N * 256);
#pragma unroll
  for (int di = 0; di < 8; ++di) {
    size_t rowo = (size_t)(d0 + dg * 8 + di) * 256 + cg * 8;
    *(float4*)(outp + rowo) = make_float4(acc[di][0], acc[di][1], acc[di][2], acc[di][3]);
    *(float4*)(outp + rowo + 4) = make_float4(acc[di][4], acc[di][5], acc[di][6], acc[di][7]);
  }
}

// ---------- layer1 finalize: h1post = elu(sum(partials)/Z + bias1) ----------
__global__ __launch_bounds__(256) void fin1K(const float* __restrict__ partials, const float* __restrict__ z1,
                                             const float* __restrict__ bias1, float* __restrict__ h1post) {
  int i = blockIdx.x * 256 + threadIdx.x;
  int d = i >> 8, c = i & 255;
  float s = 0.f;
#pragma unroll
  for (int q = 0; q < 8; ++q) s += partials[(size_t)q * N * 256 + i];
  float a = s / z1[d * 4 + (c >> 6)] + bias1[c];
  h1post[i] = a > 0.f ? a : __expf(a) - 1.f;
}

// ---------- layer2 features: hh2 = h1post @ W2, a_s2, a_d2 ----------
__global__ __launch_bounds__(256) void h2K(const float* __restrict__ h1post, const float* __restrict__ W2,
                                           const float* __restrict__ att_src2, const float* __restrict__ att_dst2,
                                           float* __restrict__ hh2, float* __restrict__ a_s2, float* __restrict__ a_d2) {
  __shared__ float hr[4][256];
  int tid = threadIdx.x;
  int n0 = blockIdx.x * 4;
  for (int t = tid; t < 1024; t += 256) hr[t >> 8][t & 255] = h1post[(size_t)n0 * 256 + t];
  __syncthreads();
  int c = tid & 63, nl = tid >> 6;
  float acc = 0.f;
  for (int k = 0; k < 256; ++k) acc += hr[nl][k] * W2[k * 64 + c];
  hh2[(size_t)(n0 + nl) * 64 + c] = acc;
  float ps = acc * att_src2[c], pd = acc * att_dst2[c];
#pragma unroll
  for (int off = 32; off > 0; off >>= 1) { ps += __shfl_down(ps, off); pd += __shfl_down(pd, off); }
  if (c == 0) { a_s2[n0 + nl] = ps; a_d2[n0 + nl] = pd; }
}

// ---------- layer2 softmax stats ----------
__global__ __launch_bounds__(256) void stats2K(const float* __restrict__ aggT, const float* __restrict__ a_s2,
                                               const float* __restrict__ a_d2, const float* __restrict__ meanE,
                                               const float* __restrict__ we,
                                               float* __restrict__ m2, float* __restrict__ z2) {
  int tid = threadIdx.x;
  int d = blockIdx.x;
  float adv = a_d2[d], me = meanE[d], wE = we[4];
  float m = -1e30f, z = 0.f;
  const float* arow = aggT + (size_t)d * N;
#pragma unroll 1
  for (int s = tid; s < N; s += 256) {
    float av = arow[s];
    float ev; bool inc;
    if (s == d) { ev = me; inc = true; } else { ev = av; inc = av > 0.f; }
    if (inc) {
      float l = lrelu(a_s2[s] + adv + ev * wE);
      float nm = fmaxf(m, l);
      z = z * __expf(m - nm) + __expf(l - nm);
      m = nm;
    }
  }
#pragma unroll
  for (int off = 32; off > 0; off >>= 1) {
    float mo = __shfl_down(m, off);
    float zo = __shfl_down(z, off);
    float nm = fmaxf(m, mo);
    z = z * __expf(m - nm) + zo * __expf(mo - nm);
    m = nm;
  }
  __shared__ float sm[4], sz[4];
  int lane = tid & 63, wid = tid >> 6;
  if (lane == 0) { sm[wid] = m; sz[wid] = z; }
  __syncthreads();
  if (tid == 0) {
    float M = -1e30f, Z = 0.f;
#pragma unroll
    for (int w = 0; w < 4; ++w) {
      float nm = fmaxf(M, sm[w]);
      Z = Z * __expf(M - nm) + sz[w] * __expf(sm[w] - nm);
      M = nm;
    }
    m2[d] = M; z2[d] = Z;
  }
}

// ---------- layer2 PV ----------
__global__ __launch_bounds__(256) void pv2K(const float* __restrict__ aggT, const float* __restrict__ hh2,
                                            const float* __restrict__ a_s2, const float* __restrict__ a_d2,
                                            const float* __restrict__ m2, const float* __restrict__ meanE,
                                            const float* __restrict__ we, float* __restrict__ partials) {
  __shared__ float pL[128][17];
  __shared__ float hT[64][17];
  int tid = threadIdx.x;
  int d0 = blockIdx.x * 128;
  int sBeg = blockIdx.y * 128;
  int dg = tid & 15;   // FMA: dd = dg + 16*di
  int cg = tid >> 4;   // FMA: c = cg*4 + ci
  int ssp = tid & 15, dq = tid >> 4;  // p-compute: dd = dq*8 + q
  float wE = we[4];
  float acc[8][4];
#pragma unroll
  for (int i = 0; i < 8; ++i)
#pragma unroll
    for (int j = 0; j < 4; ++j) acc[i][j] = 0.f;

#pragma unroll 1
  for (int s0 = sBeg; s0 < sBeg + 128; s0 += 16) {
    for (int t = tid; t < 1024; t += 256) { int c = t & 63, r = t >> 6; hT[c][r] = hh2[(size_t)(s0 + r) * 64 + c]; }
    {
      int s = s0 + ssp;
      float asv = a_s2[s];
#pragma unroll
      for (int q = 0; q < 8; ++q) {
        int dd = dq * 8 + q;
        int d = d0 + dd;
        float av = aggT[(size_t)d * N + s];
        float ev; bool inc;
        if (s == d) { ev = meanE[d]; inc = true; } else { ev = av; inc = av > 0.f; }
        float l = lrelu(asv + a_d2[d] + ev * wE);
        pL[dd][ssp] = inc ? __expf(l - m2[d]) : 0.f;
      }
    }
    __syncthreads();
#pragma unroll
    for (int ss = 0; ss < 16; ++ss) {
      float hv[4], pv[8];
#pragma unroll
      for (int i = 0; i < 4; ++i) hv[i] = hT[cg * 4 + i][ss];
#pragma unroll
      for (int i = 0; i < 8; ++i) pv[i] = pL[dg + 16 * i][ss];
#pragma unroll
      for (int di = 0; di < 8; ++di)
#pragma unroll
        for (int ci = 0; ci < 4; ++ci) acc[di][ci] += pv[di] * hv[ci];
    }
    __syncthreads();
  }
  float* outp = partials + (size_t)blockIdx.y * ((size_t)N * 64);
#pragma unroll
  for (int di = 0; di < 8; ++di) {
    size_t rowo = (size_t)(d0 + dg + 16 * di) * 64 + cg * 4;
    *(float4*)(outp + rowo) = make_float4(acc[di][0], acc[di][1], acc[di][2], acc[di][3]);
  }
}

// ---------- layer2 finalize ----------
__global__ __launch_bounds__(256) void fin2K(const float* __restrict__ partials, const float* __restrict__ z2,
                                             const float* __restrict__ bias2, float* __restrict__ h2post) {
  int i = blockIdx.x * 256 + threadIdx.x;
  int d = i >> 6, c = i & 63;
  float s = 0.f;
#pragma unroll
  for (int q = 0; q < 16; ++q) s += partials[(size_t)q * N * 64 + i];
  float a = s / z2[d] + bias2[c];
  h2post[i] = a > 0.f ? a : __expf(a) - 1.f;
}

// ---------- pool + final linear ----------
__global__ __launch_bounds__(256) void poolK(const float* __restrict__ h2post, const int* __restrict__ bidx,
                                             const float* __restrict__ W_lin, const float* __restrict__ b_lin,
                                             float* __restrict__ out) {
  __shared__ float red[4][64];
  __shared__ float cntA[4];
  __shared__ float gsh[64];
  int tid = threadIdx.x;
  int b = blockIdx.x;
  int c = tid & 63, g = tid >> 6;
  float s = 0.f, cnt = 0.f;
  for (int n = g; n < N; n += 4) {
    if (bidx[n] == b) {
      s += h2post[(size_t)n * 64 + c];
      cnt += 1.f;
    }
  }
  red[g][c] = s;
  if (c == 0) cntA[g] = cnt;
  __syncthreads();
  if (g == 0) {
    float tot = red[0][c] + red[1][c] + red[2][c] + red[3][c];
    float ct = cntA[0] + cntA[1] + cntA[2] + cntA[3];
    gsh[c] = tot / fmaxf(ct, 1.f);
  }
  __syncthreads();
  if (tid < 10) {
    float o = b_lin[tid];
    for (int k = 0; k < 64; ++k) o += gsh[k] * W_lin[k * 10 + tid];
    out[b * 10 + tid] = o;
  }
}

extern "C" void kernel_launch(void* const* d_in, const int* in_sizes, int n_in,
                              void* d_out, int out_size, void* d_ws, size_t ws_size,
                              hipStream_t stream) {
  const float* x        = (const float*)d_in[0];
  const float* attn     = (const float*)d_in[1];
  const int*   bidx     = (const int*)d_in[2];
  const float* w_agg    = (const float*)d_in[3];
  const float* b_agg    = (const float*)d_in[4];
  const float* W1       = (const float*)d_in[5];
  const float* att_src1 = (const float*)d_in[6];
  const float* att_dst1 = (const float*)d_in[7];
  const float* We1      = (const float*)d_in[8];
  const float* att_e1   = (const float*)d_in[9];
  const float* bias1    = (const float*)d_in[10];
  const float* W2       = (const float*)d_in[11];
  const float* att_src2 = (const float*)d_in[12];
  const float* att_dst2 = (const float*)d_in[13];
  const float* We2      = (const float*)d_in[14];
  const float* att_e2   = (const float*)d_in[15];
  const float* bias2    = (const float*)d_in[16];
  const float* W_lin    = (const float*)d_in[17];
  const float* b_lin    = (const float*)d_in[18];

  float* out = (float*)d_out;
  float* edge_out = out + 80;

  float* w = (float*)d_ws;
  size_t o = 0;
  float* aggT   = w + o; o += (size_t)N * N;
  float* colSum = w + o; o += N;          // colSum + colCnt contiguous for weZeroK
  float* colCnt = w + o; o += N;
  float* meanE  = w + o; o += N;
  float* wev    = w + o; o += 8;
  float* h1     = w + o; o += (size_t)N * 256;   // also reused as h1post after pv1K
  float* a_s1   = w + o; o += (size_t)N * 4;
  float* a_d1   = w + o; o += (size_t)N * 4;
  float* m1     = w + o; o += (size_t)N * 4;
  float* z1     = w + o; o += (size_t)N * 4;
  float* hh2    = w + o; o += (size_t)N * 64;    // also reused as h2post after pv2K
  float* a_s2   = w + o; o += N;
  float* a_d2   = w + o; o += N;
  float* m2     = w + o; o += N;
  float* z2     = w + o; o += N;
  float* partials = w + o; o += (size_t)8 * N * 256;  // pv2 reuses (needs 16*N*64 = half)

  float* h1post = h1;   // safe: fin1K does not read h1
  float* h2post = hh2;  // safe: fin2K does not read hh2

  weZeroK<<<16, 256, 0, stream>>>(colSum, We1, att_e1, We2, att_e2, wev);
  aggK<<<dim3(64, 64), dim3(32, 8), 0, stream>>>(attn, w_agg, b_agg, edge_out, aggT, colSum, colCnt);
  meanK<<<8, 256, 0, stream>>>(colSum, colCnt, meanE);
  h1K<<<512, 256, 0, stream>>>(x, W1, att_src1, att_dst1, h1, a_s1, a_d1);
  stats1K<<<2048, 256, 0, stream>>>(aggT, a_s1, a_d1, meanE, wev, m1, z1);
  pv1K<<<dim3(32, 8), 256, 0, stream>>>(aggT, h1, a_s1, a_d1, m1, meanE, wev, partials);
  fin1K<<<2048, 256, 0, stream>>>(partials, z1, bias1, h1post);
  h2K<<<512, 256, 0, stream>>>(h1post, W2, att_src2, att_dst2, hh2, a_s2, a_d2);
  stats2K<<<2048, 256, 0, stream>>>(aggT, a_s2, a_d2, meanE, wev, m2, z2);
  pv2K<<<dim3(16, 16), 256, 0, stream>>>(aggT, hh2, a_s2, a_d2, m2, meanE, wev, partials);
  fin2K<<<512, 256, 0, stream>>>(partials, z2, bias2, h2post);
  poolK<<<NG, 256, 0, stream>>>(h2post, bidx, W_lin, b_lin, out);
}

// Round 3
// 548.489 us; speedup vs baseline: 1.1174x; 1.1174x over previous
//
#include <hip/hip_runtime.h>

#define N 2048
#define NG 8

__device__ __forceinline__ float lrelu(float x) { return x > 0.f ? x : 0.2f * x; }

// ---------- prep: zero colSum/colCnt/z1/z2, compute we1[4], we2 ----------
// zbase layout: [colSum N][colCnt N][z1 4N][z2 N] = 7N floats
__global__ __launch_bounds__(256) void weZeroK(float* __restrict__ zbase,
                                               const float* __restrict__ We1, const float* __restrict__ att_e1,
                                               const float* __restrict__ We2, const float* __restrict__ att_e2,
                                               float* __restrict__ we) {
  int tid = threadIdx.x;
  int i = blockIdx.x * 256 + tid;
  if (i < 7 * N) zbase[i] = 0.f;
  if (blockIdx.x == 0) {
    float v1 = We1[tid] * att_e1[tid];
#pragma unroll
    for (int off = 32; off > 0; off >>= 1) v1 += __shfl_down(v1, off);
    int lane = tid & 63, wid = tid >> 6;
    if (lane == 0) we[wid] = v1;
    float v2 = (tid < 64) ? We2[tid] * att_e2[tid] : 0.f;
#pragma unroll
    for (int off = 32; off > 0; off >>= 1) v2 += __shfl_down(v2, off);
    if (tid == 0) we[4] = v2;
  }
}

// ---------- agg: 1x1 conv, edge_attr, transposed relu(agg), column stats ----------
__global__ __launch_bounds__(256) void aggK(const float* __restrict__ attn,
                                            const float* __restrict__ w_agg,
                                            const float* __restrict__ b_agg,
                                            float* __restrict__ edge_out,
                                            float* __restrict__ aggT,
                                            float* __restrict__ colSum,
                                            float* __restrict__ colCnt) {
  __shared__ float tile[32][33];
  __shared__ float wsh[12];
  __shared__ float cs[32];
  __shared__ float cc[32];
  int tx = threadIdx.x, ty = threadIdx.y;
  int tid = ty * 32 + tx;
  if (tid < 12) wsh[tid] = w_agg[tid];
  if (tid < 32) { cs[tid] = 0.f; cc[tid] = 0.f; }
  __syncthreads();
  int i0 = blockIdx.y * 32, j0 = blockIdx.x * 32;
  int j = j0 + tx;
  float bb = b_agg[0];
#pragma unroll
  for (int r = 0; r < 4; ++r) {
    int li = ty + 8 * r;
    int i = i0 + li;
    const float* p = attn + (size_t)i * N + j;
    float v = bb;
#pragma unroll
    for (int k = 0; k < 12; ++k) v += wsh[k] * p[(size_t)k * N * N];
    float e = v > 0.f ? v : 0.f;
    edge_out[(size_t)i * N + j] = e;
    tile[li][tx] = e;
    if (e > 0.f && i != j) { atomicAdd(&cs[tx], e); atomicAdd(&cc[tx], 1.f); }
  }
  __syncthreads();
#pragma unroll
  for (int r = 0; r < 4; ++r) {
    int lj = ty + 8 * r;
    aggT[(size_t)(j0 + lj) * N + i0 + tx] = tile[tx][lj];
  }
  if (tid < 32) {
    atomicAdd(&colSum[j0 + tid], cs[tid]);
    atomicAdd(&colCnt[j0 + tid], cc[tid]);
  }
}

// ---------- layer1 features: h1 = x @ W1, a_s1, a_d1 ----------
__global__ __launch_bounds__(256) void h1K(const float* __restrict__ x, const float* __restrict__ W1,
                                           const float* __restrict__ att_src1, const float* __restrict__ att_dst1,
                                           float* __restrict__ h1, float* __restrict__ a_s1, float* __restrict__ a_d1) {
  __shared__ float xr[4][128];
  int tid = threadIdx.x;
  int n0 = blockIdx.x * 4;
  for (int t = tid; t < 512; t += 256) xr[t >> 7][t & 127] = x[n0 * 128 + t];
  __syncthreads();
  float acc[4] = {0.f, 0.f, 0.f, 0.f};
  for (int k = 0; k < 128; ++k) {
    float wv = W1[k * 256 + tid];
#pragma unroll
    for (int r = 0; r < 4; ++r) acc[r] += xr[r][k] * wv;
  }
  float asw = att_src1[tid], adw = att_dst1[tid];
  int lane = tid & 63, head = tid >> 6;
#pragma unroll
  for (int r = 0; r < 4; ++r) {
    h1[(size_t)(n0 + r) * 256 + tid] = acc[r];
    float ps = acc[r] * asw, pd = acc[r] * adw;
#pragma unroll
    for (int off = 32; off > 0; off >>= 1) { ps += __shfl_down(ps, off); pd += __shfl_down(pd, off); }
    if (lane == 0) { a_s1[(n0 + r) * 4 + head] = ps; a_d1[(n0 + r) * 4 + head] = pd; }
  }
}

// ---------- layer1 PV (unnormalized softmax, z via atomics) ----------
// partials[y][d][c] = sum_{s in chunk y} exp(logit) * h1[s][c]
__global__ __launch_bounds__(256) void pv1K(const float* __restrict__ aggT, const float* __restrict__ h1,
                                            const float* __restrict__ a_s1, const float* __restrict__ a_d1,
                                            const float* __restrict__ colSum, const float* __restrict__ colCnt,
                                            const float* __restrict__ we,
                                            float* __restrict__ partials, float* __restrict__ z1) {
  __shared__ float hT[16][260];   // [ss][c]   c = 0..255
  __shared__ float pL[16][260];   // [ss][h*64+dd]
  int tid = threadIdx.x;
  int d0 = blockIdx.x * 64;
  int sBeg = blockIdx.y * 256;
  float w0 = we[0], w1 = we[1], w2 = we[2], w3 = we[3];
  // p-compute indexing
  int ssp = tid & 15, dq = tid >> 4;   // dd = dq*4+q
  float4 ad4[4];
  float me_[4];
#pragma unroll
  for (int q = 0; q < 4; ++q) {
    int d = d0 + dq * 4 + q;
    ad4[q] = *(const float4*)(a_d1 + d * 4);
    float c = colCnt[d];
    me_[q] = c > 0.f ? colSum[d] / c : 0.f;
  }
  float zac[4][4];
#pragma unroll
  for (int q = 0; q < 4; ++q)
#pragma unroll
    for (int h = 0; h < 4; ++h) zac[q][h] = 0.f;
  // FMA indexing
  int dg = tid & 7;
  int cb = (tid >> 3) * 8;     // global channel base (includes head)
  int hh = tid >> 6;           // head (wave-uniform)
  float acc[8][8];
#pragma unroll
  for (int i = 0; i < 8; ++i)
#pragma unroll
    for (int j = 0; j < 8; ++j) acc[i][j] = 0.f;

  int c4 = (tid & 63) * 4;
  int rb = (tid >> 6) * 4;

#pragma unroll 1
  for (int s0 = sBeg; s0 < sBeg + 256; s0 += 16) {
    // stage hT (per-wave contiguous rows -> conflict-free b128 writes)
#pragma unroll
    for (int p4 = 0; p4 < 4; ++p4) {
      int r = rb + p4;
      *(float4*)(&hT[r][c4]) = *(const float4*)(h1 + (size_t)(s0 + r) * 256 + c4);
    }
    // p-compute
    {
      int s = s0 + ssp;
      float4 as4 = *(const float4*)(a_s1 + s * 4);
      float pq[4][4];
#pragma unroll
      for (int q = 0; q < 4; ++q) {
        int d = d0 + dq * 4 + q;
        float av = aggT[(size_t)d * N + s];
        float ev; bool inc;
        if (s == d) { ev = me_[q]; inc = true; } else { ev = av; inc = av > 0.f; }
        float p0 = inc ? __expf(lrelu(as4.x + ad4[q].x + ev * w0)) : 0.f;
        float p1 = inc ? __expf(lrelu(as4.y + ad4[q].y + ev * w1)) : 0.f;
        float p2 = inc ? __expf(lrelu(as4.z + ad4[q].z + ev * w2)) : 0.f;
        float p3 = inc ? __expf(lrelu(as4.w + ad4[q].w + ev * w3)) : 0.f;
        pq[0][q] = p0; pq[1][q] = p1; pq[2][q] = p2; pq[3][q] = p3;
        zac[q][0] += p0; zac[q][1] += p1; zac[q][2] += p2; zac[q][3] += p3;
      }
#pragma unroll
      for (int h = 0; h < 4; ++h)
        *(float4*)(&pL[ssp][h * 64 + dq * 4]) = make_float4(pq[h][0], pq[h][1], pq[h][2], pq[h][3]);
    }
    __syncthreads();
#pragma unroll
    for (int ss = 0; ss < 16; ++ss) {
      float4 pA = *(const float4*)(&pL[ss][hh * 64 + dg * 8]);
      float4 pB = *(const float4*)(&pL[ss][hh * 64 + dg * 8 + 4]);
      float4 hA = *(const float4*)(&hT[ss][cb]);
      float4 hB = *(const float4*)(&hT[ss][cb + 4]);
      float pv[8] = {pA.x, pA.y, pA.z, pA.w, pB.x, pB.y, pB.z, pB.w};
      float hv[8] = {hA.x, hA.y, hA.z, hA.w, hB.x, hB.y, hB.z, hB.w};
#pragma unroll
      for (int di = 0; di < 8; ++di)
#pragma unroll
        for (int ci = 0; ci < 8; ++ci) acc[di][ci] += pv[di] * hv[ci];
    }
    __syncthreads();
  }
  float* outp = partials + (size_t)blockIdx.y * ((size_t)N * 256);
#pragma unroll
  for (int di = 0; di < 8; ++di) {
    size_t rowo = (size_t)(d0 + dg * 8 + di) * 256 + cb;
    *(float4*)(outp + rowo) = make_float4(acc[di][0], acc[di][1], acc[di][2], acc[di][3]);
    *(float4*)(outp + rowo + 4) = make_float4(acc[di][4], acc[di][5], acc[di][6], acc[di][7]);
  }
  // z reduction over ssp (16-lane groups), then atomics
#pragma unroll
  for (int q = 0; q < 4; ++q)
#pragma unroll
    for (int h = 0; h < 4; ++h) {
      float v = zac[q][h];
      v += __shfl_down(v, 8); v += __shfl_down(v, 4);
      v += __shfl_down(v, 2); v += __shfl_down(v, 1);
      if (ssp == 0) atomicAdd(&z1[(d0 + dq * 4 + q) * 4 + h], v);
    }
}

// ---------- layer2 features fused with layer1 finalize ----------
__global__ __launch_bounds__(256) void h2K(const float* __restrict__ partials, const float* __restrict__ z1,
                                           const float* __restrict__ bias1,
                                           const float* __restrict__ W2,
                                           const float* __restrict__ att_src2, const float* __restrict__ att_dst2,
                                           float* __restrict__ hh2, float* __restrict__ a_s2, float* __restrict__ a_d2) {
  __shared__ float hr[4][256];
  int tid = threadIdx.x;
  int n0 = blockIdx.x * 4;
  // fin1: h1post = elu(sum(partials)/z1 + bias1), straight into LDS
  for (int e = tid; e < 1024; e += 256) {
    int node = e >> 8, c = e & 255;
    size_t base = (size_t)(n0 + node) * 256 + c;
    float sAcc = 0.f;
#pragma unroll
    for (int q = 0; q < 8; ++q) sAcc += partials[(size_t)q * N * 256 + base];
    float a = sAcc / z1[(n0 + node) * 4 + (c >> 6)] + bias1[c];
    hr[node][c] = a > 0.f ? a : __expf(a) - 1.f;
  }
  __syncthreads();
  int c = tid & 63, nl = tid >> 6;
  float acc = 0.f;
  for (int k = 0; k < 256; ++k) acc += hr[nl][k] * W2[k * 64 + c];
  hh2[(size_t)(n0 + nl) * 64 + c] = acc;
  float ps = acc * att_src2[c], pd = acc * att_dst2[c];
#pragma unroll
  for (int off = 32; off > 0; off >>= 1) { ps += __shfl_down(ps, off); pd += __shfl_down(pd, off); }
  if (c == 0) { a_s2[n0 + nl] = ps; a_d2[n0 + nl] = pd; }
}

// ---------- layer2 PV (unnormalized, z via atomics) ----------
__global__ __launch_bounds__(256) void pv2K(const float* __restrict__ aggT, const float* __restrict__ hh2,
                                            const float* __restrict__ a_s2, const float* __restrict__ a_d2,
                                            const float* __restrict__ colSum, const float* __restrict__ colCnt,
                                            const float* __restrict__ we,
                                            float* __restrict__ partials, float* __restrict__ z2) {
  __shared__ float hT[16][68];    // [ss][c]  c = 0..63
  __shared__ float pL[16][132];   // [ss][dd] dd = 0..127
  int tid = threadIdx.x;
  int d0 = blockIdx.x * 128;
  int sBeg = blockIdx.y * 128;
  float wE = we[4];
  int ssp = tid & 15, dq = tid >> 4;   // dd = dq*8+q
  float adv[8], me_[8];
#pragma unroll
  for (int q = 0; q < 8; ++q) {
    int d = d0 + dq * 8 + q;
    adv[q] = a_d2[d];
    float c = colCnt[d];
    me_[q] = c > 0.f ? colSum[d] / c : 0.f;
  }
  float zac[8];
#pragma unroll
  for (int q = 0; q < 8; ++q) zac[q] = 0.f;
  int dg = tid & 15;   // d = d0 + dg*8 + di
  int cg = tid >> 4;   // c = cg*4 + ci
  float acc[8][4];
#pragma unroll
  for (int i = 0; i < 8; ++i)
#pragma unroll
    for (int j = 0; j < 4; ++j) acc[i][j] = 0.f;

  int stR = tid >> 4, stC = (tid & 15) * 4;

#pragma unroll 1
  for (int s0 = sBeg; s0 < sBeg + 128; s0 += 16) {
    *(float4*)(&hT[stR][stC]) = *(const float4*)(hh2 + (size_t)(s0 + stR) * 64 + stC);
    {
      int s = s0 + ssp;
      float asv = a_s2[s];
      float pq[8];
#pragma unroll
      for (int q = 0; q < 8; ++q) {
        int d = d0 + dq * 8 + q;
        float av = aggT[(size_t)d * N + s];
        float ev; bool inc;
        if (s == d) { ev = me_[q]; inc = true; } else { ev = av; inc = av > 0.f; }
        float p = inc ? __expf(lrelu(asv + adv[q] + ev * wE)) : 0.f;
        pq[q] = p;
        zac[q] += p;
      }
      *(float4*)(&pL[ssp][dq * 8])     = make_float4(pq[0], pq[1], pq[2], pq[3]);
      *(float4*)(&pL[ssp][dq * 8 + 4]) = make_float4(pq[4], pq[5], pq[6], pq[7]);
    }
    __syncthreads();
#pragma unroll
    for (int ss = 0; ss < 16; ++ss) {
      float4 pA = *(const float4*)(&pL[ss][dg * 8]);
      float4 pB = *(const float4*)(&pL[ss][dg * 8 + 4]);
      float4 hA = *(const float4*)(&hT[ss][cg * 4]);
      float pv[8] = {pA.x, pA.y, pA.z, pA.w, pB.x, pB.y, pB.z, pB.w};
      float hv[4] = {hA.x, hA.y, hA.z, hA.w};
#pragma unroll
      for (int di = 0; di < 8; ++di)
#pragma unroll
        for (int ci = 0; ci < 4; ++ci) acc[di][ci] += pv[di] * hv[ci];
    }
    __syncthreads();
  }
  float* outp = partials + (size_t)blockIdx.y * ((size_t)N * 64);
#pragma unroll
  for (int di = 0; di < 8; ++di) {
    size_t rowo = (size_t)(d0 + dg * 8 + di) * 64 + cg * 4;
    *(float4*)(outp + rowo) = make_float4(acc[di][0], acc[di][1], acc[di][2], acc[di][3]);
  }
#pragma unroll
  for (int q = 0; q < 8; ++q) {
    float v = zac[q];
    v += __shfl_down(v, 8); v += __shfl_down(v, 4);
    v += __shfl_down(v, 2); v += __shfl_down(v, 1);
    if (ssp == 0) atomicAdd(&z2[d0 + dq * 8 + q], v);
  }
}

// ---------- layer2 finalize ----------
__global__ __launch_bounds__(256) void fin2K(const float* __restrict__ partials, const float* __restrict__ z2,
                                             const float* __restrict__ bias2, float* __restrict__ h2post) {
  int i = blockIdx.x * 256 + threadIdx.x;
  int d = i >> 6, c = i & 63;
  float s = 0.f;
#pragma unroll
  for (int q = 0; q < 16; ++q) s += partials[(size_t)q * N * 64 + i];
  float a = s / z2[d] + bias2[c];
  h2post[i] = a > 0.f ? a : __expf(a) - 1.f;
}

// ---------- pool + final linear ----------
__global__ __launch_bounds__(256) void poolK(const float* __restrict__ h2post, const int* __restrict__ bidx,
                                             const float* __restrict__ W_lin, const float* __restrict__ b_lin,
                                             float* __restrict__ out) {
  __shared__ float red[4][64];
  __shared__ float cntA[4];
  __shared__ float gsh[64];
  int tid = threadIdx.x;
  int b = blockIdx.x;
  int c = tid & 63, g = tid >> 6;
  float s = 0.f, cnt = 0.f;
  for (int n = g; n < N; n += 4) {
    if (bidx[n] == b) {
      s += h2post[(size_t)n * 64 + c];
      cnt += 1.f;
    }
  }
  red[g][c] = s;
  if (c == 0) cntA[g] = cnt;
  __syncthreads();
  if (g == 0) {
    float tot = red[0][c] + red[1][c] + red[2][c] + red[3][c];
    float ct = cntA[0] + cntA[1] + cntA[2] + cntA[3];
    gsh[c] = tot / fmaxf(ct, 1.f);
  }
  __syncthreads();
  if (tid < 10) {
    float o = b_lin[tid];
    for (int k = 0; k < 64; ++k) o += gsh[k] * W_lin[k * 10 + tid];
    out[b * 10 + tid] = o;
  }
}

extern "C" void kernel_launch(void* const* d_in, const int* in_sizes, int n_in,
                              void* d_out, int out_size, void* d_ws, size_t ws_size,
                              hipStream_t stream) {
  const float* x        = (const float*)d_in[0];
  const float* attn     = (const float*)d_in[1];
  const int*   bidx     = (const int*)d_in[2];
  const float* w_agg    = (const float*)d_in[3];
  const float* b_agg    = (const float*)d_in[4];
  const float* W1       = (const float*)d_in[5];
  const float* att_src1 = (const float*)d_in[6];
  const float* att_dst1 = (const float*)d_in[7];
  const float* We1      = (const float*)d_in[8];
  const float* att_e1   = (const float*)d_in[9];
  const float* bias1    = (const float*)d_in[10];
  const float* W2       = (const float*)d_in[11];
  const float* att_src2 = (const float*)d_in[12];
  const float* att_dst2 = (const float*)d_in[13];
  const float* We2      = (const float*)d_in[14];
  const float* att_e2   = (const float*)d_in[15];
  const float* bias2    = (const float*)d_in[16];
  const float* W_lin    = (const float*)d_in[17];
  const float* b_lin    = (const float*)d_in[18];

  float* out = (float*)d_out;
  float* edge_out = out + 80;

  // Workspace budget: keep <= 36.3 MB (round-1 proven). Total here:
  // 4194304 + 14344 + 524288 + 16384 + 131072 + 4096 + 4194304 = 9,078,792 floats = 36.3 MB
  float* w = (float*)d_ws;
  size_t o = 0;
  float* aggT   = w + o; o += (size_t)N * N;
  float* zb     = w + o; o += 7 * N;       // colSum | colCnt | z1(4N) | z2(N)
  float* wev    = w + o; o += 8;
  float* h1     = w + o; o += (size_t)N * 256;
  float* a_s1   = w + o; o += (size_t)N * 4;
  float* a_d1   = w + o; o += (size_t)N * 4;
  float* hh2    = w + o; o += (size_t)N * 64;
  float* a_s2   = w + o; o += N;
  float* a_d2   = w + o; o += N;
  float* partials = w + o; o += (size_t)8 * N * 256;  // pv2 reuses (needs 16*N*64 = 1/4)

  float* colSum = zb;
  float* colCnt = zb + N;
  float* z1     = zb + 2 * N;
  float* z2     = zb + 6 * N;
  float* h2post = hh2;   // safe: fin2K does not read hh2 (pv2K done by then)

  weZeroK<<<56, 256, 0, stream>>>(zb, We1, att_e1, We2, att_e2, wev);
  aggK<<<dim3(64, 64), dim3(32, 8), 0, stream>>>(attn, w_agg, b_agg, edge_out, aggT, colSum, colCnt);
  h1K<<<512, 256, 0, stream>>>(x, W1, att_src1, att_dst1, h1, a_s1, a_d1);
  pv1K<<<dim3(32, 8), 256, 0, stream>>>(aggT, h1, a_s1, a_d1, colSum, colCnt, wev, partials, z1);
  h2K<<<512, 256, 0, stream>>>(partials, z1, bias1, W2, att_src2, att_dst2, hh2, a_s2, a_d2);
  pv2K<<<dim3(16, 16), 256, 0, stream>>>(aggT, hh2, a_s2, a_d2, colSum, colCnt, wev, partials, z2);
  fin2K<<<512, 256, 0, stream>>>(partials, z2, bias2, h2post);
  poolK<<<NG, 256, 0, stream>>>(h2post, bidx, W_lin, b_lin, out);
}

// Round 4
// 547.659 us; speedup vs baseline: 1.1191x; 1.0015x over previous
//
#include <hip/hip_runtime.h>

#define N 2048
#define NG 8

__device__ __forceinline__ float lrelu(float x) { return x > 0.f ? x : 0.2f * x; }

// ---------- agg: 1x1 conv, edge_attr, transposed relu(agg), column stats ----------
__global__ __launch_bounds__(256) void aggK(const float* __restrict__ attn,
                                            const float* __restrict__ w_agg,
                                            const float* __restrict__ b_agg,
                                            float* __restrict__ edge_out,
                                            float* __restrict__ aggT,
                                            float* __restrict__ colSum,
                                            float* __restrict__ colCnt) {
  __shared__ float tile[32][33];
  __shared__ float wsh[12];
  __shared__ float cs[32];
  __shared__ float cc[32];
  int tx = threadIdx.x, ty = threadIdx.y;
  int tid = ty * 32 + tx;
  if (tid < 12) wsh[tid] = w_agg[tid];
  if (tid < 32) { cs[tid] = 0.f; cc[tid] = 0.f; }
  __syncthreads();
  int i0 = blockIdx.y * 32, j0 = blockIdx.x * 32;
  int j = j0 + tx;
  float bb = b_agg[0];
#pragma unroll
  for (int r = 0; r < 4; ++r) {
    int li = ty + 8 * r;
    int i = i0 + li;
    const float* p = attn + (size_t)i * N + j;
    float v = bb;
#pragma unroll
    for (int k = 0; k < 12; ++k) v += wsh[k] * p[(size_t)k * N * N];
    float e = v > 0.f ? v : 0.f;
    edge_out[(size_t)i * N + j] = e;
    tile[li][tx] = e;
    if (e > 0.f && i != j) { atomicAdd(&cs[tx], e); atomicAdd(&cc[tx], 1.f); }
  }
  __syncthreads();
#pragma unroll
  for (int r = 0; r < 4; ++r) {
    int lj = ty + 8 * r;
    aggT[(size_t)(j0 + lj) * N + i0 + tx] = tile[tx][lj];
  }
  if (tid < 32) {
    atomicAdd(&colSum[j0 + tid], cs[tid]);
    atomicAdd(&colCnt[j0 + tid], cc[tid]);
  }
}

// ---------- layer1 features: h1 = x @ W1, a_s1, a_d1; block 0 also computes we[] ----------
__global__ __launch_bounds__(256) void h1K(const float* __restrict__ x, const float* __restrict__ W1,
                                           const float* __restrict__ att_src1, const float* __restrict__ att_dst1,
                                           const float* __restrict__ We1, const float* __restrict__ att_e1,
                                           const float* __restrict__ We2, const float* __restrict__ att_e2,
                                           float* __restrict__ h1, float* __restrict__ a_s1, float* __restrict__ a_d1,
                                           float* __restrict__ we) {
  __shared__ float xr[4][128];
  int tid = threadIdx.x;
  int n0 = blockIdx.x * 4;
  if (blockIdx.x == 0) {
    float v1 = We1[tid] * att_e1[tid];
#pragma unroll
    for (int off = 32; off > 0; off >>= 1) v1 += __shfl_down(v1, off);
    int lane = tid & 63, wid = tid >> 6;
    if (lane == 0) we[wid] = v1;
    float v2 = (tid < 64) ? We2[tid] * att_e2[tid] : 0.f;
#pragma unroll
    for (int off = 32; off > 0; off >>= 1) v2 += __shfl_down(v2, off);
    if (tid == 0) we[4] = v2;
  }
  for (int t = tid; t < 512; t += 256) xr[t >> 7][t & 127] = x[n0 * 128 + t];
  __syncthreads();
  float acc[4] = {0.f, 0.f, 0.f, 0.f};
  for (int k = 0; k < 128; ++k) {
    float wv = W1[k * 256 + tid];
#pragma unroll
    for (int r = 0; r < 4; ++r) acc[r] += xr[r][k] * wv;
  }
  float asw = att_src1[tid], adw = att_dst1[tid];
  int lane = tid & 63, head = tid >> 6;
#pragma unroll
  for (int r = 0; r < 4; ++r) {
    h1[(size_t)(n0 + r) * 256 + tid] = acc[r];
    float ps = acc[r] * asw, pd = acc[r] * adw;
#pragma unroll
    for (int off = 32; off > 0; off >>= 1) { ps += __shfl_down(ps, off); pd += __shfl_down(pd, off); }
    if (lane == 0) { a_s1[(n0 + r) * 4 + head] = ps; a_d1[(n0 + r) * 4 + head] = pd; }
  }
}

// ---------- layer1 PV (unnormalized softmax, z via atomics) ----------
// grid (32,16): 64-d tile x 128-s chunk; 2 blocks/CU for phase overlap
__global__ __launch_bounds__(256) void pv1K(const float* __restrict__ aggT, const float* __restrict__ h1,
                                            const float* __restrict__ a_s1, const float* __restrict__ a_d1,
                                            const float* __restrict__ colSum, const float* __restrict__ colCnt,
                                            const float* __restrict__ we,
                                            float* __restrict__ partials, float* __restrict__ z1) {
  __shared__ float hT[16][260];   // [ss][c]   c = 0..255
  __shared__ float pL[16][260];   // [ss][h*64+dd]
  int tid = threadIdx.x;
  int d0 = blockIdx.x * 64;
  int sBeg = blockIdx.y * 128;
  float w0 = we[0], w1 = we[1], w2 = we[2], w3 = we[3];
  // p-compute indexing
  int ssp = tid & 15, dq = tid >> 4;   // dd = dq*4+q
  float4 ad4[4];
  float me_[4];
#pragma unroll
  for (int q = 0; q < 4; ++q) {
    int d = d0 + dq * 4 + q;
    ad4[q] = *(const float4*)(a_d1 + d * 4);
    float c = colCnt[d];
    me_[q] = c > 0.f ? colSum[d] / c : 0.f;
  }
  float zac[4][4];
#pragma unroll
  for (int q = 0; q < 4; ++q)
#pragma unroll
    for (int h = 0; h < 4; ++h) zac[q][h] = 0.f;
  // FMA indexing
  int dg = tid & 7;
  int cb = (tid >> 3) * 8;     // global channel base (includes head)
  int hh = tid >> 6;           // head (wave-uniform)
  float acc[8][8];
#pragma unroll
  for (int i = 0; i < 8; ++i)
#pragma unroll
    for (int j = 0; j < 8; ++j) acc[i][j] = 0.f;

  int c4 = (tid & 63) * 4;
  int rb = (tid >> 6) * 4;

#pragma unroll 1
  for (int s0 = sBeg; s0 < sBeg + 128; s0 += 16) {
    // stage hT (per-wave contiguous rows -> conflict-free b128 writes)
#pragma unroll
    for (int p4 = 0; p4 < 4; ++p4) {
      int r = rb + p4;
      *(float4*)(&hT[r][c4]) = *(const float4*)(h1 + (size_t)(s0 + r) * 256 + c4);
    }
    // p-compute
    {
      int s = s0 + ssp;
      float4 as4 = *(const float4*)(a_s1 + s * 4);
      float pq[4][4];
#pragma unroll
      for (int q = 0; q < 4; ++q) {
        int d = d0 + dq * 4 + q;
        float av = aggT[(size_t)d * N + s];
        float ev; bool inc;
        if (s == d) { ev = me_[q]; inc = true; } else { ev = av; inc = av > 0.f; }
        float p0 = inc ? __expf(lrelu(as4.x + ad4[q].x + ev * w0)) : 0.f;
        float p1 = inc ? __expf(lrelu(as4.y + ad4[q].y + ev * w1)) : 0.f;
        float p2 = inc ? __expf(lrelu(as4.z + ad4[q].z + ev * w2)) : 0.f;
        float p3 = inc ? __expf(lrelu(as4.w + ad4[q].w + ev * w3)) : 0.f;
        pq[0][q] = p0; pq[1][q] = p1; pq[2][q] = p2; pq[3][q] = p3;
        zac[q][0] += p0; zac[q][1] += p1; zac[q][2] += p2; zac[q][3] += p3;
      }
#pragma unroll
      for (int h = 0; h < 4; ++h)
        *(float4*)(&pL[ssp][h * 64 + dq * 4]) = make_float4(pq[h][0], pq[h][1], pq[h][2], pq[h][3]);
    }
    __syncthreads();
#pragma unroll
    for (int ss = 0; ss < 16; ++ss) {
      float4 pA = *(const float4*)(&pL[ss][hh * 64 + dg * 8]);
      float4 pB = *(const float4*)(&pL[ss][hh * 64 + dg * 8 + 4]);
      float4 hA = *(const float4*)(&hT[ss][cb]);
      float4 hB = *(const float4*)(&hT[ss][cb + 4]);
      float pv[8] = {pA.x, pA.y, pA.z, pA.w, pB.x, pB.y, pB.z, pB.w};
      float hv[8] = {hA.x, hA.y, hA.z, hA.w, hB.x, hB.y, hB.z, hB.w};
#pragma unroll
      for (int di = 0; di < 8; ++di)
#pragma unroll
        for (int ci = 0; ci < 8; ++ci) acc[di][ci] += pv[di] * hv[ci];
    }
    __syncthreads();
  }
  float* outp = partials + (size_t)blockIdx.y * ((size_t)N * 256);
#pragma unroll
  for (int di = 0; di < 8; ++di) {
    size_t rowo = (size_t)(d0 + dg * 8 + di) * 256 + cb;
    *(float4*)(outp + rowo) = make_float4(acc[di][0], acc[di][1], acc[di][2], acc[di][3]);
    *(float4*)(outp + rowo + 4) = make_float4(acc[di][4], acc[di][5], acc[di][6], acc[di][7]);
  }
  // z reduction over ssp (16-lane groups), then atomics
#pragma unroll
  for (int q = 0; q < 4; ++q)
#pragma unroll
    for (int h = 0; h < 4; ++h) {
      float v = zac[q][h];
      v += __shfl_down(v, 8); v += __shfl_down(v, 4);
      v += __shfl_down(v, 2); v += __shfl_down(v, 1);
      if (ssp == 0) atomicAdd(&z1[(d0 + dq * 4 + q) * 4 + h], v);
    }
}

// ---------- layer2 features fused with layer1 finalize ----------
__global__ __launch_bounds__(256) void h2K(const float* __restrict__ partials, const float* __restrict__ z1,
                                           const float* __restrict__ bias1,
                                           const float* __restrict__ W2,
                                           const float* __restrict__ att_src2, const float* __restrict__ att_dst2,
                                           float* __restrict__ hh2, float* __restrict__ a_s2, float* __restrict__ a_d2) {
  __shared__ float hr[4][256];
  int tid = threadIdx.x;
  int n0 = blockIdx.x * 4;
  // fin1: h1post = elu(sum(partials)/z1 + bias1), straight into LDS
  for (int e = tid; e < 1024; e += 256) {
    int node = e >> 8, c = e & 255;
    size_t base = (size_t)(n0 + node) * 256 + c;
    float sAcc = 0.f;
#pragma unroll
    for (int q = 0; q < 16; ++q) sAcc += partials[(size_t)q * N * 256 + base];
    float a = sAcc / z1[(n0 + node) * 4 + (c >> 6)] + bias1[c];
    hr[node][c] = a > 0.f ? a : __expf(a) - 1.f;
  }
  __syncthreads();
  int c = tid & 63, nl = tid >> 6;
  float acc = 0.f;
  for (int k = 0; k < 256; ++k) acc += hr[nl][k] * W2[k * 64 + c];
  hh2[(size_t)(n0 + nl) * 64 + c] = acc;
  float ps = acc * att_src2[c], pd = acc * att_dst2[c];
#pragma unroll
  for (int off = 32; off > 0; off >>= 1) { ps += __shfl_down(ps, off); pd += __shfl_down(pd, off); }
  if (c == 0) { a_s2[n0 + nl] = ps; a_d2[n0 + nl] = pd; }
}

// ---------- layer2 PV (unnormalized, z via atomics), grid (16,32) ----------
__global__ __launch_bounds__(256) void pv2K(const float* __restrict__ aggT, const float* __restrict__ hh2,
                                            const float* __restrict__ a_s2, const float* __restrict__ a_d2,
                                            const float* __restrict__ colSum, const float* __restrict__ colCnt,
                                            const float* __restrict__ we,
                                            float* __restrict__ partials, float* __restrict__ z2) {
  __shared__ float hT[16][68];    // [ss][c]  c = 0..63
  __shared__ float pL[16][132];   // [ss][dd] dd = 0..127
  int tid = threadIdx.x;
  int d0 = blockIdx.x * 128;
  int sBeg = blockIdx.y * 64;
  float wE = we[4];
  int ssp = tid & 15, dq = tid >> 4;   // dd = dq*8+q
  float adv[8], me_[8];
#pragma unroll
  for (int q = 0; q < 8; ++q) {
    int d = d0 + dq * 8 + q;
    adv[q] = a_d2[d];
    float c = colCnt[d];
    me_[q] = c > 0.f ? colSum[d] / c : 0.f;
  }
  float zac[8];
#pragma unroll
  for (int q = 0; q < 8; ++q) zac[q] = 0.f;
  int dg = tid & 15;   // d = d0 + dg*8 + di
  int cg = tid >> 4;   // c = cg*4 + ci
  float acc[8][4];
#pragma unroll
  for (int i = 0; i < 8; ++i)
#pragma unroll
    for (int j = 0; j < 4; ++j) acc[i][j] = 0.f;

  int stR = tid >> 4, stC = (tid & 15) * 4;

#pragma unroll 1
  for (int s0 = sBeg; s0 < sBeg + 64; s0 += 16) {
    *(float4*)(&hT[stR][stC]) = *(const float4*)(hh2 + (size_t)(s0 + stR) * 64 + stC);
    {
      int s = s0 + ssp;
      float asv = a_s2[s];
      float pq[8];
#pragma unroll
      for (int q = 0; q < 8; ++q) {
        int d = d0 + dq * 8 + q;
        float av = aggT[(size_t)d * N + s];
        float ev; bool inc;
        if (s == d) { ev = me_[q]; inc = true; } else { ev = av; inc = av > 0.f; }
        float p = inc ? __expf(lrelu(asv + adv[q] + ev * wE)) : 0.f;
        pq[q] = p;
        zac[q] += p;
      }
      *(float4*)(&pL[ssp][dq * 8])     = make_float4(pq[0], pq[1], pq[2], pq[3]);
      *(float4*)(&pL[ssp][dq * 8 + 4]) = make_float4(pq[4], pq[5], pq[6], pq[7]);
    }
    __syncthreads();
#pragma unroll
    for (int ss = 0; ss < 16; ++ss) {
      float4 pA = *(const float4*)(&pL[ss][dg * 8]);
      float4 pB = *(const float4*)(&pL[ss][dg * 8 + 4]);
      float4 hA = *(const float4*)(&hT[ss][cg * 4]);
      float pv[8] = {pA.x, pA.y, pA.z, pA.w, pB.x, pB.y, pB.z, pB.w};
      float hv[4] = {hA.x, hA.y, hA.z, hA.w};
#pragma unroll
      for (int di = 0; di < 8; ++di)
#pragma unroll
        for (int ci = 0; ci < 4; ++ci) acc[di][ci] += pv[di] * hv[ci];
    }
    __syncthreads();
  }
  float* outp = partials + (size_t)blockIdx.y * ((size_t)N * 64);
#pragma unroll
  for (int di = 0; di < 8; ++di) {
    size_t rowo = (size_t)(d0 + dg * 8 + di) * 64 + cg * 4;
    *(float4*)(outp + rowo) = make_float4(acc[di][0], acc[di][1], acc[di][2], acc[di][3]);
  }
#pragma unroll
  for (int q = 0; q < 8; ++q) {
    float v = zac[q];
    v += __shfl_down(v, 8); v += __shfl_down(v, 4);
    v += __shfl_down(v, 2); v += __shfl_down(v, 1);
    if (ssp == 0) atomicAdd(&z2[d0 + dq * 8 + q], v);
  }
}

// ---------- layer2 finalize ----------
__global__ __launch_bounds__(256) void fin2K(const float* __restrict__ partials, const float* __restrict__ z2,
                                             const float* __restrict__ bias2, float* __restrict__ h2post) {
  int i = blockIdx.x * 256 + threadIdx.x;
  int d = i >> 6, c = i & 63;
  float s = 0.f;
#pragma unroll
  for (int q = 0; q < 32; ++q) s += partials[(size_t)q * N * 64 + i];
  float a = s / z2[d] + bias2[c];
  h2post[i] = a > 0.f ? a : __expf(a) - 1.f;
}

// ---------- pool + final linear ----------
__global__ __launch_bounds__(256) void poolK(const float* __restrict__ h2post, const int* __restrict__ bidx,
                                             const float* __restrict__ W_lin, const float* __restrict__ b_lin,
                                             float* __restrict__ out) {
  __shared__ float red[4][64];
  __shared__ float cntA[4];
  __shared__ float gsh[64];
  int tid = threadIdx.x;
  int b = blockIdx.x;
  int c = tid & 63, g = tid >> 6;
  float s = 0.f, cnt = 0.f;
  for (int n = g; n < N; n += 4) {
    if (bidx[n] == b) {
      s += h2post[(size_t)n * 64 + c];
      cnt += 1.f;
    }
  }
  red[g][c] = s;
  if (c == 0) cntA[g] = cnt;
  __syncthreads();
  if (g == 0) {
    float tot = red[0][c] + red[1][c] + red[2][c] + red[3][c];
    float ct = cntA[0] + cntA[1] + cntA[2] + cntA[3];
    gsh[c] = tot / fmaxf(ct, 1.f);
  }
  __syncthreads();
  if (tid < 10) {
    float o = b_lin[tid];
    for (int k = 0; k < 64; ++k) o += gsh[k] * W_lin[k * 10 + tid];
    out[b * 10 + tid] = o;
  }
}

extern "C" void kernel_launch(void* const* d_in, const int* in_sizes, int n_in,
                              void* d_out, int out_size, void* d_ws, size_t ws_size,
                              hipStream_t stream) {
  const float* x        = (const float*)d_in[0];
  const float* attn     = (const float*)d_in[1];
  const int*   bidx     = (const int*)d_in[2];
  const float* w_agg    = (const float*)d_in[3];
  const float* b_agg    = (const float*)d_in[4];
  const float* W1       = (const float*)d_in[5];
  const float* att_src1 = (const float*)d_in[6];
  const float* att_dst1 = (const float*)d_in[7];
  const float* We1      = (const float*)d_in[8];
  const float* att_e1   = (const float*)d_in[9];
  const float* bias1    = (const float*)d_in[10];
  const float* W2       = (const float*)d_in[11];
  const float* att_src2 = (const float*)d_in[12];
  const float* att_dst2 = (const float*)d_in[13];
  const float* We2      = (const float*)d_in[14];
  const float* att_e2   = (const float*)d_in[15];
  const float* bias2    = (const float*)d_in[16];
  const float* W_lin    = (const float*)d_in[17];
  const float* b_lin    = (const float*)d_in[18];

  float* out = (float*)d_out;
  float* edge_out = out + 80;

  // ws_size ~768 MiB (profiled poison fill). Total used here ~53 MB.
  float* w = (float*)d_ws;
  size_t o = 0;
  float* aggT   = w + o; o += (size_t)N * N;
  float* zb     = w + o; o += 7 * N;       // colSum | colCnt | z1(4N) | z2(N)
  float* wev    = w + o; o += 8;
  float* h1     = w + o; o += (size_t)N * 256;
  float* a_s1   = w + o; o += (size_t)N * 4;
  float* a_d1   = w + o; o += (size_t)N * 4;
  float* hh2    = w + o; o += (size_t)N * 64;
  float* a_s2   = w + o; o += N;
  float* a_d2   = w + o; o += N;
  float* partials = w + o; o += (size_t)16 * N * 256;  // pv2 reuses (needs 32*N*64 = half)

  float* colSum = zb;
  float* colCnt = zb + N;
  float* z1     = zb + 2 * N;
  float* z2     = zb + 6 * N;
  float* h2post = hh2;   // safe: fin2K does not read hh2 (pv2K done by then)

  hipMemsetAsync(zb, 0, 7 * N * sizeof(float), stream);
  aggK<<<dim3(64, 64), dim3(32, 8), 0, stream>>>(attn, w_agg, b_agg, edge_out, aggT, colSum, colCnt);
  h1K<<<512, 256, 0, stream>>>(x, W1, att_src1, att_dst1, We1, att_e1, We2, att_e2, h1, a_s1, a_d1, wev);
  pv1K<<<dim3(32, 16), 256, 0, stream>>>(aggT, h1, a_s1, a_d1, colSum, colCnt, wev, partials, z1);
  h2K<<<512, 256, 0, stream>>>(partials, z1, bias1, W2, att_src2, att_dst2, hh2, a_s2, a_d2);
  pv2K<<<dim3(16, 32), 256, 0, stream>>>(aggT, hh2, a_s2, a_d2, colSum, colCnt, wev, partials, z2);
  fin2K<<<512, 256, 0, stream>>>(partials, z2, bias2, h2post);
  poolK<<<NG, 256, 0, stream>>>(h2post, bidx, W_lin, b_lin, out);
}